// Round 18
// baseline (163.316 us; speedup 1.0000x reference)
//
#include <hip/hip_runtime.h>
#include <stdint.h>

// Hash-NMS via perfect direct-indexed bucket table (no keys, no CAS).
//
// slot_raw = cum[kw]*T + nx[kw]*cum[kh] + iy*nx[kw] + ix  is a bijection of
// (ix,iy,iw,ih) == the reference's (key_hi,key_lo) classes.  slot =
// (slot_raw * ODD) mod 2^22 is ALSO a bijection -> spreads hot buckets
// across cache lines (fixed round-6's line-serialized RMWs).
//
// Pass 1 (insert, 4 boxes/thread): compute 4 slots (ILP on the log chains),
//   issue 4 independent hint-loads (4x memory-level parallelism per lane,
//   one waitcnt), then <=4 conditional fire-and-forget atomicMax of
//   (conf_bits<<32 | ~idx). Hint skip is exact: slot values are monotone
//   increasing and cross-box equality is impossible (idx in value).
//   Round 8/9 measured: hint+swizzle cut insert 169 -> 53 us; this round
//   targets the residual dependent-load latency via ILP.
// Pass 2 (sweep): stream the TABLE. Nonzero slot holds the winner verbatim:
//   idx = ~lo32, conf bits = hi32. Scatter out_conf[idx], out_keep[idx]=1;
//   rest stays 0 from the d_out memset.
//
// NUMERICS (bit-exact vs NumPy f32 ref, verified rounds 5/6/8/9): log in
// double rounded to f32 (= correctly-rounded = glibc); pow via host LUT
// computed with the IDENTICAL double->f32->*9.6f sequence; all other ops
// IEEE-exact f32.

struct HashParams { int nx[13]; int cum[13]; float cell[13]; int T; };

#define TBL_BITS 22
#define TBL_SLOTS (1u << TBL_BITS)
#define TBL_MASK  (TBL_SLOTS - 1u)
#define SWZ_MUL   0x9E3779B1u
#define BOX_PER_THREAD 4

typedef float f32x4 __attribute__((ext_vector_type(4)));  // nontemporal-ok vec4

__device__ __forceinline__ unsigned long long pack_val(float conf, unsigned int i) {
    // conf in (0,1): positive f32 bits monotone. Max packed == (max conf,
    // then min idx) == lexsort (-conf, idx) winner.
    return ((unsigned long long)__float_as_uint(conf) << 32)
         | (unsigned long long)(~i);
}

__global__ __launch_bounds__(256)
void hnms_insert(const f32x4* __restrict__ rects,
                 const float* __restrict__ conf,
                 unsigned long long* __restrict__ tvals,
                 int n, HashParams P)
{
    __shared__ int   s_nx[13], s_cum[13];
    __shared__ float s_cell[13];
    int t = threadIdx.x;
    if (t < 13) { s_nx[t] = P.nx[t]; s_cum[t] = P.cum[t]; s_cell[t] = P.cell[t]; }
    __syncthreads();

    int base = (blockIdx.x * blockDim.x + t) * BOX_PER_THREAD;
    if (base >= n) return;
    int cnt = min(BOX_PER_THREAD, n - base);

    const float log_alpha = (float)log((double)0.7f);   // compile-time const
    const float inv_log_a = 1.0f / log_alpha;

    unsigned int       slot[BOX_PER_THREAD];
    unsigned long long mine[BOX_PER_THREAD];

    #pragma unroll
    for (int k = 0; k < BOX_PER_THREAD; ++k) {
        if (k >= cnt) break;
        int i = base + k;
        f32x4 r = __builtin_nontemporal_load(&rects[i]);   // don't evict table
        float c = __builtin_nontemporal_load(&conf[i]);

        float lw = (float)log((double)(r.z * 0.0625f));    // CR f32 via double
        float lh = (float)log((double)(r.w * 0.0625f));
        int iw = (int)rintf(lw * inv_log_a);
        int ih = (int)rintf(lh * inv_log_a);

        int kw = min(max(iw + 8, 0), 12);
        int kh = min(max(ih + 8, 0), 12);
        float cell_w = s_cell[kw];                         // 9.6f*(f32)pow(...)
        float cell_h = s_cell[kh];
        int ix = (int)rintf(r.x / cell_w - 0.5f);
        int iy = (int)rintf(r.y / cell_h - 0.5f);

        int nxw = s_nx[kw];
        ix = min(max(ix, 0), nxw - 1);        // inactive for in-range data
        iy = min(max(iy, 0), s_nx[kh] - 1);

        unsigned int raw = (unsigned int)(s_cum[kw] * P.T + nxw * s_cum[kh]
                                          + iy * nxw + ix);
        slot[k] = (raw * SWZ_MUL) & TBL_MASK;              // bijective swizzle
        mine[k] = pack_val(c, (unsigned int)i);
    }

    // Issue all hint-loads back-to-back: independent -> overlapped latency.
    unsigned long long cur[BOX_PER_THREAD];
    #pragma unroll
    for (int k = 0; k < BOX_PER_THREAD; ++k) {
        if (k >= cnt) break;
        cur[k] = __hip_atomic_load(&tvals[slot[k]], __ATOMIC_RELAXED,
                                   __HIP_MEMORY_SCOPE_AGENT);
    }

    #pragma unroll
    for (int k = 0; k < BOX_PER_THREAD; ++k) {
        if (k >= cnt) break;
        if (cur[k] < mine[k])
            atomicMax(&tvals[slot[k]], mine[k]);           // fire-and-forget
    }
}

__global__ __launch_bounds__(256)
void hnms_sweep(const ulonglong2* __restrict__ tvals2,
                float* __restrict__ out_conf,
                float* __restrict__ out_keep)
{
    const unsigned total = TBL_SLOTS / 2;               // ulonglong2 elements
    unsigned stride = gridDim.x * blockDim.x;
    for (unsigned s = blockIdx.x * blockDim.x + threadIdx.x; s < total; s += stride) {
        ulonglong2 v = tvals2[s];
        if (v.x) {
            unsigned idx = ~(unsigned)v.x;
            out_conf[idx] = __uint_as_float((unsigned)(v.x >> 32));
            out_keep[idx] = 1.0f;
        }
        if (v.y) {
            unsigned idx = ~(unsigned)v.y;
            out_conf[idx] = __uint_as_float((unsigned)(v.y >> 32));
            out_keep[idx] = 1.0f;
        }
    }
}

extern "C" void kernel_launch(void* const* d_in, const int* in_sizes, int n_in,
                              void* d_out, int out_size, void* d_ws, size_t ws_size,
                              hipStream_t stream)
{
    const float* rects = (const float*)d_in[0];   // (N,4) f32
    const float* conf  = (const float*)d_in[1];   // (N,)  f32
    const int n = in_sizes[1];

    // Host-side layout + cell LUT. cell[k] replicates the device/reference
    // sequence bit-for-bit: f64 CR pow -> f32 round -> f32 mul by 9.6f.
    HashParams P;
    {
        int off = 0;
        for (int k = 0; k < 13; ++k) {
            int iw = k - 8;
            float p32  = (float)pow((double)0.7f, (double)iw);
            float cell = 9.6f * p32;
            int nxk = (int)rint(1333.0 / (double)cell - 0.5) + 1 + 3; // margin
            P.cell[k] = cell;
            P.nx[k]   = nxk;
            P.cum[k]  = off;
            off += nxk;
        }
        P.T = off;   // ~1956; T*T ~ 3.83M <= 2^22 slots
    }

    unsigned long long* tvals = (unsigned long long*)d_ws;  // 33.5 MB

    float* out_conf = (float*)d_out;
    float* out_keep = out_conf + n;

    // ws/out re-poisoned 0xAA each call -> zero both (0 < any packed value;
    // non-winners must read 0.0f).
    (void)hipMemsetAsync(tvals, 0x00, (size_t)TBL_SLOTS * 8, stream);
    (void)hipMemsetAsync(d_out, 0x00, (size_t)2 * n * sizeof(float), stream);

    const int block = 256;
    const int per_blk = block * BOX_PER_THREAD;
    const int grid_i  = (n + per_blk - 1) / per_blk;
    hnms_insert<<<grid_i, block, 0, stream>>>(
        (const f32x4*)rects, conf, tvals, n, P);
    hnms_sweep<<<2048, block, 0, stream>>>(
        (const ulonglong2*)tvals, out_conf, out_keep);
}